// Round 1
// baseline (589.682 us; speedup 1.0000x reference)
//
#include <hip/hip_runtime.h>
#include <math.h>

#define S_LEN 2048
#define D_MODEL 4096
#define NH 32
#define NKV 4
#define HD 128
#define KV_W (NKV * HD)        // 512
#define QK_W (D_MODEL + KV_W)  // 4608
#define QKV_W (QK_W + KV_W)    // 5120 fused q+k+v projection width

typedef float f32x4 __attribute__((ext_vector_type(4)));
typedef __bf16 bf16x8 __attribute__((ext_vector_type(8)));

// async global->LDS 16B copy. LDS dest = wave-uniform base + lane*16.
__device__ __forceinline__ void async16(const __bf16* g, __bf16* l) {
    __builtin_amdgcn_global_load_lds(
        (const __attribute__((address_space(1))) unsigned int*)g,
        (__attribute__((address_space(3))) unsigned int*)l, 16, 0, 0);
}

// ---------------- cast fp32 -> bf16 ----------------
__global__ void cast_f32_bf16(const float* __restrict__ in, __bf16* __restrict__ out, int n) {
    int i = (blockIdx.x * blockDim.x + threadIdx.x) * 4;
    if (i >= n) return;
    float4 v = *reinterpret_cast<const float4*>(in + i);
    out[i + 0] = (__bf16)v.x;
    out[i + 1] = (__bf16)v.y;
    out[i + 2] = (__bf16)v.z;
    out[i + 3] = (__bf16)v.w;
}

// ---------------- transpose + cast: in[R][C] f32 -> out[C][R] bf16 ----------------
__global__ void transpose_cast(const float* __restrict__ in, __bf16* __restrict__ out, int R, int C) {
    __shared__ float tile[64][65];
    const int tid = threadIdx.x;
    const int bx = blockIdx.x * 64, by = blockIdx.y * 64;
#pragma unroll
    for (int i = 0; i < 4; i++) {
        int idx = tid + i * 256;          // 0..1023
        int r = idx >> 4, c4 = (idx & 15) * 4;
        float4 v = *(const float4*)(in + (size_t)(by + r) * C + bx + c4);
        tile[r][c4 + 0] = v.x; tile[r][c4 + 1] = v.y;
        tile[r][c4 + 2] = v.z; tile[r][c4 + 3] = v.w;
    }
    __syncthreads();
#pragma unroll
    for (int i = 0; i < 2; i++) {
        int idx = tid + i * 256;          // 0..511
        int oc = idx >> 3, r8 = (idx & 7) * 8;
        bf16x8 v;
#pragma unroll
        for (int e = 0; e < 8; e++) v[e] = (__bf16)tile[r8 + e][oc];
        *(bf16x8*)(out + (size_t)(bx + oc) * R + by + r8) = v;
    }
}

// ---------------- 256x256 8-phase bf16 MFMA GEMM: C = A[M][K] * Bt[N][K]^T ----------------
// 8 waves (2M x 4N), per-wave output = two 64-row strips x 64 cols. BK=64,
// LDS 128 KiB (2 dbuf x (A 256x64 + B 256x64) bf16), XOR-swizzled 16B chunks
// (phys = logical ^ (row&7)) applied on the global SOURCE of global_load_lds
// (dest must stay linear) and on the ds_read address.
// Phase (qm,qn) reads only A-half qm / B-half qn -> per-phase one half-tile
// stage into a fully-consumed region:
//   p0: stage A1(g+1)->nxt   p1: stage B1(g+1)->nxt
//   p2: stage A0(g+2)->cur   p3: stage B0(g+2)->cur
// One counted s_waitcnt vmcnt(4) per K-tile (never 0 in steady state); raw
// s_barrier only (no __syncthreads -> no vmcnt(0) drain); setprio around MFMA.
// MODE 0: f32 [M][N] to Cp.   MODE 1: fused QKV epilogue (bf16 Q|K at Cp, V^T at Cp2).
template <int MODE>
__global__ __launch_bounds__(512, 2) void gemm256(const __bf16* __restrict__ A,
                                                  const __bf16* __restrict__ Bt,
                                                  void* __restrict__ Cp, void* __restrict__ Cp2,
                                                  int M, int N, int K) {
    __shared__ __bf16 aL[2][256 * 64];
    __shared__ __bf16 bL[2][256 * 64];

    const int tid = threadIdx.x;
    const int wave = tid >> 6, lane = tid & 63;
    const int quad = lane >> 4, l16 = lane & 15;
    const int wm = wave >> 2, wn = wave & 3;   // 2 x 4 wave grid

    // XCD-aware bijective block swizzle (nwg % 8 == 0 for all grids used here)
    const int gx = gridDim.x;
    const int nwg = gx * gridDim.y;
    int id = blockIdx.y * gx + blockIdx.x;
    id = (id & 7) * (nwg >> 3) + (id >> 3);
    const int n0 = (id % gx) * 256, m0 = (id / gx) * 256;

    const int NT = K >> 6;  // K-tiles of 64

    // per-thread staging source: row (t>>3) within a 64-row batch, pre-swizzled k-chunk
    const int srow = tid >> 3;
    const int schunk = (tid & 7) ^ (srow & 7);
    const __bf16* pA = A + (size_t)(m0 + srow) * K + schunk * 8;
    const __bf16* pB = Bt + (size_t)(n0 + srow) * K + schunk * 8;

    auto stageA = [&](int buf, int h, int kt) {
#pragma unroll
        for (int b = 0; b < 2; ++b)
            async16(pA + (size_t)(h * 128 + b * 64) * K + kt * 64,
                    &aL[buf][(h * 128 + b * 64) * 64 + tid * 8]);
    };
    auto stageB = [&](int buf, int h, int kt) {
#pragma unroll
        for (int b = 0; b < 2; ++b)
            async16(pB + (size_t)(h * 128 + b * 64) * K + kt * 64,
                    &bL[buf][(h * 128 + b * 64) * 64 + tid * 8]);
    };

    f32x4 acc[8][4];
#pragma unroll
    for (int i = 0; i < 8; i++)
#pragma unroll
        for (int j = 0; j < 4; j++) acc[i][j] = (f32x4)0.0f;

    const int arow0 = wm * 64 + l16;           // + qm*128 + mi*16
    const int brow0 = wn * 32 + l16;           // + qn*128 + ni*16
    const int ach0 = ((0 + quad) ^ (l16 & 7)) * 8;  // kk=0 phys chunk (elems)
    const int ach1 = ((4 + quad) ^ (l16 & 7)) * 8;  // kk=1

    // prologue: K-tile 0 fully + K-tile 1 first halves; vmcnt(4) retires K-tile 0
    stageA(0, 0, 0); stageB(0, 0, 0);
    stageA(0, 1, 0); stageB(0, 1, 0);
    stageA(1, 0, 1); stageB(1, 0, 1);
    asm volatile("s_waitcnt vmcnt(4)" ::: "memory");
    __builtin_amdgcn_sched_barrier(0);
    __builtin_amdgcn_s_barrier();

#define GPHASE(QM, QN, STAGE_STMT, END_STMT)                                             \
    {                                                                                    \
        bf16x8 af[4][2], bf[2][2];                                                       \
        _Pragma("unroll") for (int mi = 0; mi < 4; ++mi) {                               \
            const __bf16* ab = &aL[cur][((QM)*128 + arow0 + mi * 16) * 64];              \
            af[mi][0] = *(const bf16x8*)(ab + ach0);                                     \
            af[mi][1] = *(const bf16x8*)(ab + ach1);                                     \
        }                                                                                \
        _Pragma("unroll") for (int ni = 0; ni < 2; ++ni) {                               \
            const __bf16* bb = &bL[cur][((QN)*128 + brow0 + ni * 16) * 64];              \
            bf[ni][0] = *(const bf16x8*)(bb + ach0);                                     \
            bf[ni][1] = *(const bf16x8*)(bb + ach1);                                     \
        }                                                                                \
        STAGE_STMT                                                                       \
        __builtin_amdgcn_s_barrier();                                                    \
        asm volatile("s_waitcnt lgkmcnt(0)" ::: "memory");                               \
        __builtin_amdgcn_sched_barrier(0);                                               \
        __builtin_amdgcn_s_setprio(1);                                                   \
        _Pragma("unroll") for (int mi = 0; mi < 4; ++mi)                                 \
            _Pragma("unroll") for (int ni = 0; ni < 2; ++ni) {                           \
                acc[(QM)*4 + mi][(QN)*2 + ni] = __builtin_amdgcn_mfma_f32_16x16x32_bf16( \
                    af[mi][0], bf[ni][0], acc[(QM)*4 + mi][(QN)*2 + ni], 0, 0, 0);       \
                acc[(QM)*4 + mi][(QN)*2 + ni] = __builtin_amdgcn_mfma_f32_16x16x32_bf16( \
                    af[mi][1], bf[ni][1], acc[(QM)*4 + mi][(QN)*2 + ni], 0, 0, 0);       \
            }                                                                            \
        __builtin_amdgcn_s_setprio(0);                                                   \
        END_STMT                                                                         \
        __builtin_amdgcn_s_barrier();                                                    \
    }

    for (int g = 0; g < NT; ++g) {
        const int cur = g & 1, nxt = cur ^ 1;
        // p0 (qm=0,qn=0): A1[nxt] last read at group g-1 p3 -> safe to stage
        GPHASE(0, 0, if (g + 1 < NT) stageA(nxt, 1, g + 1);, )
        // p1 (qm=0,qn=1): B1[nxt] last read at group g-1 p3
        GPHASE(0, 1, if (g + 1 < NT) stageB(nxt, 1, g + 1);, )
        // p2 (qm=1,qn=0): A0[cur] last read at p1 (barrier-separated)
        GPHASE(1, 0, if (g + 2 < NT) stageA(cur, 0, g + 2);, )
        // p3 (qm=1,qn=1): B0[cur] last read at p2; group-end counted wait:
        // retires all 4 halves of K-tile g+1, leaves A0/B0(g+2) in flight.
        GPHASE(1, 1, if (g + 2 < NT) stageB(cur, 0, g + 2);,
               if (g + 2 < NT) { asm volatile("s_waitcnt vmcnt(4)" ::: "memory"); }
               else if (g + 1 < NT) { asm volatile("s_waitcnt vmcnt(0)" ::: "memory"); }
               __builtin_amdgcn_sched_barrier(0);)
    }
#undef GPHASE

    const bool vregion = (MODE == 1) && (n0 >= QK_W);
#pragma unroll
    for (int i = 0; i < 8; i++)
#pragma unroll
        for (int j = 0; j < 4; j++)
#pragma unroll
            for (int r = 0; r < 4; r++) {
                int gm = m0 + (i >> 2) * 128 + wm * 64 + (i & 3) * 16 + quad * 4 + r;
                int gn = n0 + (j >> 1) * 128 + wn * 32 + (j & 1) * 16 + l16;
                float v = acc[i][j][r];
                if constexpr (MODE == 0) {
                    ((float*)Cp)[(size_t)gm * N + gn] = v;
                } else {
                    if (vregion)
                        ((__bf16*)Cp2)[(size_t)(gn - QK_W) * M + gm] = (__bf16)v;
                    else
                        ((__bf16*)Cp)[(size_t)gm * QK_W + gn] = (__bf16)v;
                }
            }
}

// ---------------- YaRN RoPE (bf16 strided src, bf16 out) ----------------
__global__ void rope_cast(const __bf16* __restrict__ src, int sPitch, int sOff,
                          __bf16* __restrict__ dst, int dPitch, int H, int total) {
    int idx = blockIdx.x * blockDim.x + threadIdx.x;
    if (idx >= total) return;
    int d = idx & 63;
    int t = idx >> 6;
    int h = t % H;
    int s = t / H;

    float inv = __powf(10000.0f, -(float)d * (1.0f / 64.0f));
    float wl = 6.2831853071795864f / inv;
    float r = 163840.0f / wl;
    float gamma = fminf(fmaxf((r - 1.0f) * (1.0f / 31.0f), 0.0f), 1.0f);
    float adj = inv * ((1.0f - gamma) * (1.0f / 80.0f) + gamma);
    float ang = ((float)s * adj) / 1.1992508365439246f; // / sqrt(0.1*ln(80)+1)
    float c = cosf(ang), sn = sinf(ang);

    const __bf16* b = src + (size_t)s * sPitch + sOff + h * HD;
    __bf16* o = dst + (size_t)s * dPitch + h * HD;
    float x1 = (float)b[d], x2 = (float)b[d + 64];
    o[d] = (__bf16)(x1 * c - x2 * sn);
    o[d + 64] = (__bf16)(x2 * c + x1 * sn);
}

// ---------------- flash attention v4 (pipelined, causal, GQA, fixed-max softmax) ----------------
__global__ __launch_bounds__(256, 2) void flash_attn(const __bf16* __restrict__ Q,
                                                     const __bf16* __restrict__ Kb,
                                                     const __bf16* __restrict__ Vt,
                                                     __bf16* __restrict__ O) {
    __shared__ __bf16 k_lds[2][64 * 128];  // [key][dim], XOR-swizzled chunks, double-buffered
    __shared__ __bf16 vt_lds[128 * 64];    // [dim][key], XOR-swizzled chunks
    __shared__ __bf16 p_lds[128 * 72];     // P C-layout -> A-layout round trip

    const int tid = threadIdx.x;
    const int wave = tid >> 6, lane = tid & 63;
    const int quad = lane >> 4, l16 = lane & 15;
    const int h = blockIdx.x;
    const int ty = blockIdx.y;
    const int t = (ty < 8) ? ty : 23 - ty;
    const int qb0 = t * 128;
    const int wrow = wave * 32;
    const int kvh = h >> 3;
    const float sl2e = 0.12752039149672056f;  // (1/sqrt(128)) * log2(e)

    bf16x8 qfr[2][4];
#pragma unroll
    for (int mi = 0; mi < 2; mi++)
#pragma unroll
        for (int kk = 0; kk < 4; kk++)
            qfr[mi][kk] = *(const bf16x8*)(Q + (size_t)(qb0 + wrow + mi * 16 + l16) * D_MODEL
                                           + h * HD + kk * 32 + quad * 8);

    f32x4 acc[2][8];
#pragma unroll
    for (int mi = 0; mi < 2; mi++)
#pragma unroll
        for (int dt = 0; dt < 8; dt++) acc[mi][dt] = (f32x4)0.0f;
    float rs[2][4] = {{0.f, 0.f, 0.f, 0.f}, {0.f, 0.f, 0.f, 0.f}};

    const int nk = 2 * t + 2;

#pragma unroll
    for (int it = 0; it < 4; it++) {
        int c = tid + it * 256;
        int krow = c >> 4, kcb = c & 15;
        async16(Kb + (size_t)krow * KV_W + kvh * HD + ((kcb ^ (krow & 15)) << 3),
                k_lds[0] + c * 8);
    }
    __syncthreads();   // publish K(0)

    for (int kt = 0; kt < nk; kt++) {
        const int k0 = kt * 64;
        const int cur = kt & 1;

#pragma unroll
        for (int it = 0; it < 4; it++) {
            int c = tid + it * 256;
            int vrow = c >> 3, vcb = c & 7;
            async16(Vt + (size_t)(kvh * HD + vrow) * S_LEN + k0 + ((vcb ^ (vrow & 7)) << 3),
                    vt_lds + c * 8);
        }

        // ---- S = Q K^T from k_lds[cur] ----
        f32x4 sc[2][4];
#pragma unroll
        for (int mi = 0; mi < 2; mi++)
#pragma unroll
            for (int j = 0; j < 4; j++) sc[mi][j] = (f32x4)0.0f;
        __builtin_amdgcn_s_setprio(1);
#pragma unroll
        for (int j = 0; j < 4; j++)
#pragma unroll
            for (int kk = 0; kk < 4; kk++) {
                bf16x8 kf = *(const bf16x8*)(k_lds[cur] + (((j * 16 + l16) << 4) + ((kk * 4 + quad) ^ l16)) * 8);
                sc[0][j] = __builtin_amdgcn_mfma_f32_16x16x32_bf16(qfr[0][kk], kf, sc[0][j], 0, 0, 0);
                sc[1][j] = __builtin_amdgcn_mfma_f32_16x16x32_bf16(qfr[1][kk], kf, sc[1][j], 0, 0, 0);
            }
        __builtin_amdgcn_s_setprio(0);

        // ---- fixed-max softmax: p = exp2(s*scale*log2e), masked -> 0 ----
        const bool hasmask = (kt >= 2 * t);
#pragma unroll
        for (int mi = 0; mi < 2; mi++) {
            int rowb = qb0 + wrow + mi * 16 + quad * 4;
#pragma unroll
            for (int j = 0; j < 4; j++) {
                int kg = k0 + j * 16 + l16;
#pragma unroll
                for (int r = 0; r < 4; r++) {
                    float p = __builtin_amdgcn_exp2f(sc[mi][j][r] * sl2e);
                    if (hasmask && kg > rowb + r) p = 0.0f;
                    rs[mi][r] += p;
                    p_lds[(wrow + mi * 16 + quad * 4 + r) * 72 + j * 16 + l16] = (__bf16)p;
                }
            }
        }

        __syncthreads();   // drains V(kt) (cover: QK phase)

        if (kt + 1 < nk) {
#pragma unroll
            for (int it = 0; it < 4; it++) {
                int c = tid + it * 256;
                int krow = c >> 4, kcb = c & 15;
                async16(Kb + (size_t)(k0 + 64 + krow) * KV_W + kvh * HD + ((kcb ^ (krow & 15)) << 3),
                        k_lds[cur ^ 1] + c * 8);
            }
        }

        // ---- O += P V ----
        bf16x8 pf[2][2];
#pragma unroll
        for (int mi = 0; mi < 2; mi++)
#pragma unroll
            for (int kk = 0; kk < 2; kk++)
                pf[mi][kk] = *(const bf16x8*)(p_lds + (wrow + mi * 16 + l16) * 72 + kk * 32 + quad * 8);
        __builtin_amdgcn_s_setprio(1);
#pragma unroll
        for (int dt = 0; dt < 8; dt++)
#pragma unroll
            for (int kk = 0; kk < 2; kk++) {
                bf16x8 vf = *(const bf16x8*)(vt_lds + (((dt * 16 + l16) << 3) + ((kk * 4 + quad) ^ (l16 & 7))) * 8);
                acc[0][dt] = __builtin_amdgcn_mfma_f32_16x16x32_bf16(pf[0][kk], vf, acc[0][dt], 0, 0, 0);
                acc[1][dt] = __builtin_amdgcn_mfma_f32_16x16x32_bf16(pf[1][kk], vf, acc[1][dt], 0, 0, 0);
            }
        __builtin_amdgcn_s_setprio(0);

        __syncthreads();   // drains K(kt+1) (cover: PV phase)
    }

    float inv_l[2][4];
#pragma unroll
    for (int mi = 0; mi < 2; mi++)
#pragma unroll
        for (int r = 0; r < 4; r++) {
            float s = rs[mi][r];
#pragma unroll
            for (int m = 1; m <= 8; m <<= 1) s += __shfl_xor(s, m, 64);
            inv_l[mi][r] = 1.0f / s;
        }

#pragma unroll
    for (int mi = 0; mi < 2; mi++)
#pragma unroll
        for (int dt = 0; dt < 8; dt++)
#pragma unroll
            for (int r = 0; r < 4; r++) {
                int row = qb0 + wrow + mi * 16 + quad * 4 + r;
                int col = h * HD + dt * 16 + l16;
                O[(size_t)row * D_MODEL + col] = (__bf16)(acc[mi][dt][r] * inv_l[mi][r]);
            }
}

// ---------------- host launch ----------------
extern "C" void kernel_launch(void* const* d_in, const int* in_sizes, int n_in,
                              void* d_out, int out_size, void* d_ws, size_t ws_size,
                              hipStream_t stream) {
    const float* x = (const float*)d_in[0];
    const float* wq = (const float*)d_in[1];
    const float* wk = (const float*)d_in[2];
    const float* wv = (const float*)d_in[3];
    const float* wo = (const float*)d_in[4];
    float* out = (float*)d_out;

    char* ws = (char*)d_ws;
    size_t off = 0;
    auto alloc = [&](size_t bytes) {
        void* p = ws + off;
        off += (bytes + 255) & ~(size_t)255;
        return p;
    };
    __bf16* xb    = (__bf16*)alloc((size_t)S_LEN * D_MODEL * 2);
    __bf16* wqkvT = (__bf16*)alloc((size_t)QKV_W * D_MODEL * 2);  // [wq^T; wk^T; wv^T]
    __bf16* woT   = (__bf16*)alloc((size_t)D_MODEL * D_MODEL * 2);
    __bf16* qkb   = (__bf16*)alloc((size_t)S_LEN * QK_W * 2);     // pre-rope q|k
    __bf16* vtb   = (__bf16*)alloc((size_t)KV_W * S_LEN * 2);     // V^T
    __bf16* qb    = (__bf16*)alloc((size_t)S_LEN * D_MODEL * 2);  // post-rope Q
    __bf16* kb    = (__bf16*)alloc((size_t)S_LEN * KV_W * 2);     // post-rope K
    __bf16* ob    = (__bf16*)alloc((size_t)S_LEN * D_MODEL * 2);  // attention out

    // 1. casts / transposes
    cast_f32_bf16<<<(S_LEN * D_MODEL) / (256 * 4), 256, 0, stream>>>(x, xb, S_LEN * D_MODEL);
    transpose_cast<<<dim3(D_MODEL / 64, D_MODEL / 64), 256, 0, stream>>>(wq, wqkvT, D_MODEL, D_MODEL);
    transpose_cast<<<dim3(KV_W / 64, D_MODEL / 64), 256, 0, stream>>>(wk, wqkvT + (size_t)D_MODEL * D_MODEL, D_MODEL, KV_W);
    transpose_cast<<<dim3(KV_W / 64, D_MODEL / 64), 256, 0, stream>>>(wv, wqkvT + (size_t)QK_W * D_MODEL, D_MODEL, KV_W);
    transpose_cast<<<dim3(D_MODEL / 64, D_MODEL / 64), 256, 0, stream>>>(wo, woT, D_MODEL, D_MODEL);

    // 2. fused Q+K+V projection, 256^2 8-phase (160 blocks; bf16 out; V transposed)
    gemm256<1><<<dim3(QKV_W / 256, S_LEN / 256), 512, 0, stream>>>(xb, wqkvT, qkb, vtb, S_LEN, QKV_W, D_MODEL);

    // 3. RoPE
    rope_cast<<<(S_LEN * NH * 64) / 256, 256, 0, stream>>>(qkb, QK_W, 0, qb, D_MODEL, NH, S_LEN * NH * 64);
    rope_cast<<<(S_LEN * NKV * 64) / 256, 256, 0, stream>>>(qkb, QK_W, D_MODEL, kb, KV_W, NKV, S_LEN * NKV * 64);

    // 4. attention (512 blocks, 2/CU, complementary-tile swizzle)
    flash_attn<<<dim3(NH, 16), 256, 0, stream>>>(qb, kb, vtb, ob);

    // 5. output projection -> fp32 d_out, 256^2 8-phase (128 blocks)
    gemm256<0><<<dim3(D_MODEL / 256, S_LEN / 256), 512, 0, stream>>>(ob, woT, out, nullptr, S_LEN, D_MODEL, D_MODEL);
}

// Round 2
// 543.944 us; speedup vs baseline: 1.0841x; 1.0841x over previous
//
#include <hip/hip_runtime.h>
#include <math.h>

#define S_LEN 2048
#define D_MODEL 4096
#define NH 32
#define NKV 4
#define HD 128
#define KV_W (NKV * HD)        // 512
#define QK_W (D_MODEL + KV_W)  // 4608
#define QKV_W (QK_W + KV_W)    // 5120 fused q+k+v projection width

typedef float f32x4 __attribute__((ext_vector_type(4)));
typedef __bf16 bf16x8 __attribute__((ext_vector_type(8)));

// async global->LDS 16B copy. LDS dest = wave-uniform base + lane*16.
__device__ __forceinline__ void async16(const __bf16* g, __bf16* l) {
    __builtin_amdgcn_global_load_lds(
        (const __attribute__((address_space(1))) unsigned int*)g,
        (__attribute__((address_space(3))) unsigned int*)l, 16, 0, 0);
}

// ---------------- cast fp32 -> bf16 ----------------
__global__ void cast_f32_bf16(const float* __restrict__ in, __bf16* __restrict__ out, int n) {
    int i = (blockIdx.x * blockDim.x + threadIdx.x) * 4;
    if (i >= n) return;
    float4 v = *reinterpret_cast<const float4*>(in + i);
    out[i + 0] = (__bf16)v.x;
    out[i + 1] = (__bf16)v.y;
    out[i + 2] = (__bf16)v.z;
    out[i + 3] = (__bf16)v.w;
}

// ---------------- transpose + cast: in[R][C] f32 -> out[C][R] bf16 ----------------
__global__ void transpose_cast(const float* __restrict__ in, __bf16* __restrict__ out, int R, int C) {
    __shared__ float tile[64][65];
    const int tid = threadIdx.x;
    const int bx = blockIdx.x * 64, by = blockIdx.y * 64;
#pragma unroll
    for (int i = 0; i < 4; i++) {
        int idx = tid + i * 256;          // 0..1023
        int r = idx >> 4, c4 = (idx & 15) * 4;
        float4 v = *(const float4*)(in + (size_t)(by + r) * C + bx + c4);
        tile[r][c4 + 0] = v.x; tile[r][c4 + 1] = v.y;
        tile[r][c4 + 2] = v.z; tile[r][c4 + 3] = v.w;
    }
    __syncthreads();
#pragma unroll
    for (int i = 0; i < 2; i++) {
        int idx = tid + i * 256;          // 0..511
        int oc = idx >> 3, r8 = (idx & 7) * 8;
        bf16x8 v;
#pragma unroll
        for (int e = 0; e < 8; e++) v[e] = (__bf16)tile[r8 + e][oc];
        *(bf16x8*)(out + (size_t)(bx + oc) * R + by + r8) = v;
    }
}

// ---------------- 256x256 pipelined bf16 MFMA GEMM: C = A[M][K] * Bt[N][K]^T ----------------
// 8 waves (2M x 4N), per-wave output 128x64 (4 quadrant pieces). BK=64,
// LDS 128 KiB (2 dbuf x (A 256x64 + B 256x64) bf16), XOR-swizzled 16B chunks
// (phys = logical ^ (row&7)) applied on the global SOURCE of global_load_lds
// (dest stays linear) and on the ds_read address. Bank conflicts: 0 (verified).
//
// TWO phases per K-tile with full operand persistence (reuse-optimal:
// 24 ds_read_b128 / 64 MFMA per wave per K-tile = 0.375 reads/MFMA; the
// previous 4-quadrant split re-read A-halves -> 48 reads and made the LDS
// read pipe the critical path):
//   p0: read A0(8) + ALL B(8), MFMA A0 x B (32); stage A1,B1(g+1) -> nxt
//   p1: read A1(8) [B kept in regs],  MFMA A1 x B (32); stage A0,B0(g+2) -> cur
// One counted s_waitcnt vmcnt(4) per K-tile (retires exactly tile g+1, leaves
// A0/B0(g+2) in flight); raw s_barrier only; setprio around MFMA clusters.
// MODE 0: f32 [M][N] to Cp.   MODE 1: fused QKV epilogue (bf16 Q|K at Cp, V^T at Cp2).
template <int MODE>
__global__ __launch_bounds__(512, 2) void gemm256(const __bf16* __restrict__ A,
                                                  const __bf16* __restrict__ Bt,
                                                  void* __restrict__ Cp, void* __restrict__ Cp2,
                                                  int M, int N, int K) {
    __shared__ __bf16 aL[2][256 * 64];
    __shared__ __bf16 bL[2][256 * 64];

    const int tid = threadIdx.x;
    const int wave = tid >> 6, lane = tid & 63;
    const int quad = lane >> 4, l16 = lane & 15;
    const int wm = wave >> 2, wn = wave & 3;   // 2 x 4 wave grid

    // XCD-aware bijective block swizzle (nwg % 8 == 0 for all grids used here)
    const int gx = gridDim.x;
    const int nwg = gx * gridDim.y;
    int id = blockIdx.y * gx + blockIdx.x;
    id = (id & 7) * (nwg >> 3) + (id >> 3);
    const int n0 = (id % gx) * 256, m0 = (id / gx) * 256;

    const int NT = K >> 6;  // K-tiles of 64

    // per-thread staging source: row (t>>3) within a 64-row batch, pre-swizzled k-chunk
    const int srow = tid >> 3;
    const int schunk = (tid & 7) ^ (srow & 7);
    const __bf16* pA = A + (size_t)(m0 + srow) * K + schunk * 8;
    const __bf16* pB = Bt + (size_t)(n0 + srow) * K + schunk * 8;

    auto stageA = [&](int buf, int h, int kt) {
#pragma unroll
        for (int b = 0; b < 2; ++b)
            async16(pA + (size_t)(h * 128 + b * 64) * K + kt * 64,
                    &aL[buf][(h * 128 + b * 64) * 64 + tid * 8]);
    };
    auto stageB = [&](int buf, int h, int kt) {
#pragma unroll
        for (int b = 0; b < 2; ++b)
            async16(pB + (size_t)(h * 128 + b * 64) * K + kt * 64,
                    &bL[buf][(h * 128 + b * 64) * 64 + tid * 8]);
    };

    f32x4 acc[8][4];
#pragma unroll
    for (int i = 0; i < 8; i++)
#pragma unroll
        for (int j = 0; j < 4; j++) acc[i][j] = (f32x4)0.0f;

    const int arow0 = wm * 64 + l16;           // + qm*128 + mi*16
    const int brow0 = wn * 32 + l16;           // + qn*128 + ni*16
    const int ach0 = ((0 + quad) ^ (l16 & 7)) * 8;  // kk=0 phys chunk (elems)
    const int ach1 = ((4 + quad) ^ (l16 & 7)) * 8;  // kk=1

    // prologue: K-tile 0 fully + K-tile 1 first halves; vmcnt(4) retires K-tile 0
    stageA(0, 0, 0); stageB(0, 0, 0);
    stageA(0, 1, 0); stageB(0, 1, 0);
    stageA(1, 0, 1); stageB(1, 0, 1);
    asm volatile("s_waitcnt vmcnt(4)" ::: "memory");
    __builtin_amdgcn_sched_barrier(0);
    __builtin_amdgcn_s_barrier();

    for (int g = 0; g < NT; ++g) {
        const int cur = g & 1, nxt = cur ^ 1;
        bf16x8 bf[4][2];  // all B fragments, persistent across both phases

        // ---- phase 0: read A0 + all B; MFMA A0 x B; stage A1/B1(g+1) -> nxt ----
        {
            bf16x8 af[4][2];
#pragma unroll
            for (int mi = 0; mi < 4; ++mi) {
                const __bf16* ab = &aL[cur][(arow0 + mi * 16) * 64];
                af[mi][0] = *(const bf16x8*)(ab + ach0);
                af[mi][1] = *(const bf16x8*)(ab + ach1);
            }
#pragma unroll
            for (int qn = 0; qn < 2; ++qn)
#pragma unroll
                for (int ni = 0; ni < 2; ++ni) {
                    const __bf16* bb = &bL[cur][(qn * 128 + brow0 + ni * 16) * 64];
                    bf[qn * 2 + ni][0] = *(const bf16x8*)(bb + ach0);
                    bf[qn * 2 + ni][1] = *(const bf16x8*)(bb + ach1);
                }
            if (g + 1 < NT) { stageA(nxt, 1, g + 1); stageB(nxt, 1, g + 1); }
            __builtin_amdgcn_s_barrier();
            asm volatile("s_waitcnt lgkmcnt(0)" ::: "memory");
            __builtin_amdgcn_sched_barrier(0);
            __builtin_amdgcn_s_setprio(1);
#pragma unroll
            for (int mi = 0; mi < 4; ++mi)
#pragma unroll
                for (int nj = 0; nj < 4; ++nj) {
                    acc[mi][nj] = __builtin_amdgcn_mfma_f32_16x16x32_bf16(
                        af[mi][0], bf[nj][0], acc[mi][nj], 0, 0, 0);
                    acc[mi][nj] = __builtin_amdgcn_mfma_f32_16x16x32_bf16(
                        af[mi][1], bf[nj][1], acc[mi][nj], 0, 0, 0);
                }
            __builtin_amdgcn_s_setprio(0);
            __builtin_amdgcn_s_barrier();
        }

        // ---- phase 1: read A1 (B in regs); MFMA A1 x B; stage A0/B0(g+2) -> cur ----
        {
            bf16x8 af[4][2];
#pragma unroll
            for (int mi = 0; mi < 4; ++mi) {
                const __bf16* ab = &aL[cur][(128 + arow0 + mi * 16) * 64];
                af[mi][0] = *(const bf16x8*)(ab + ach0);
                af[mi][1] = *(const bf16x8*)(ab + ach1);
            }
            if (g + 2 < NT) { stageA(cur, 0, g + 2); stageB(cur, 0, g + 2); }
            __builtin_amdgcn_s_barrier();
            asm volatile("s_waitcnt lgkmcnt(0)" ::: "memory");
            __builtin_amdgcn_sched_barrier(0);
            __builtin_amdgcn_s_setprio(1);
#pragma unroll
            for (int mi = 0; mi < 4; ++mi)
#pragma unroll
                for (int nj = 0; nj < 4; ++nj) {
                    acc[4 + mi][nj] = __builtin_amdgcn_mfma_f32_16x16x32_bf16(
                        af[mi][0], bf[nj][0], acc[4 + mi][nj], 0, 0, 0);
                    acc[4 + mi][nj] = __builtin_amdgcn_mfma_f32_16x16x32_bf16(
                        af[mi][1], bf[nj][1], acc[4 + mi][nj], 0, 0, 0);
                }
            __builtin_amdgcn_s_setprio(0);
            // group-end counted wait: retires all 4 halves of K-tile g+1,
            // leaves A0/B0(g+2) in flight. Never 0 in steady state.
            if (g + 2 < NT) { asm volatile("s_waitcnt vmcnt(4)" ::: "memory"); }
            else if (g + 1 < NT) { asm volatile("s_waitcnt vmcnt(0)" ::: "memory"); }
            __builtin_amdgcn_sched_barrier(0);
            __builtin_amdgcn_s_barrier();
        }
    }

    const bool vregion = (MODE == 1) && (n0 >= QK_W);
#pragma unroll
    for (int i = 0; i < 8; i++)
#pragma unroll
        for (int j = 0; j < 4; j++)
#pragma unroll
            for (int r = 0; r < 4; r++) {
                int gm = m0 + (i >> 2) * 128 + wm * 64 + (i & 3) * 16 + quad * 4 + r;
                int gn = n0 + (j >> 1) * 128 + wn * 32 + (j & 1) * 16 + l16;
                float v = acc[i][j][r];
                if constexpr (MODE == 0) {
                    ((float*)Cp)[(size_t)gm * N + gn] = v;
                } else {
                    if (vregion)
                        ((__bf16*)Cp2)[(size_t)(gn - QK_W) * M + gm] = (__bf16)v;
                    else
                        ((__bf16*)Cp)[(size_t)gm * QK_W + gn] = (__bf16)v;
                }
            }
}

// ---------------- YaRN RoPE (bf16 strided src, bf16 out) ----------------
__global__ void rope_cast(const __bf16* __restrict__ src, int sPitch, int sOff,
                          __bf16* __restrict__ dst, int dPitch, int H, int total) {
    int idx = blockIdx.x * blockDim.x + threadIdx.x;
    if (idx >= total) return;
    int d = idx & 63;
    int t = idx >> 6;
    int h = t % H;
    int s = t / H;

    float inv = __powf(10000.0f, -(float)d * (1.0f / 64.0f));
    float wl = 6.2831853071795864f / inv;
    float r = 163840.0f / wl;
    float gamma = fminf(fmaxf((r - 1.0f) * (1.0f / 31.0f), 0.0f), 1.0f);
    float adj = inv * ((1.0f - gamma) * (1.0f / 80.0f) + gamma);
    float ang = ((float)s * adj) / 1.1992508365439246f; // / sqrt(0.1*ln(80)+1)
    float c = cosf(ang), sn = sinf(ang);

    const __bf16* b = src + (size_t)s * sPitch + sOff + h * HD;
    __bf16* o = dst + (size_t)s * dPitch + h * HD;
    float x1 = (float)b[d], x2 = (float)b[d + 64];
    o[d] = (__bf16)(x1 * c - x2 * sn);
    o[d + 64] = (__bf16)(x2 * c + x1 * sn);
}

// ---------------- flash attention v4 (pipelined, causal, GQA, fixed-max softmax) ----------------
__global__ __launch_bounds__(256, 2) void flash_attn(const __bf16* __restrict__ Q,
                                                     const __bf16* __restrict__ Kb,
                                                     const __bf16* __restrict__ Vt,
                                                     __bf16* __restrict__ O) {
    __shared__ __bf16 k_lds[2][64 * 128];  // [key][dim], XOR-swizzled chunks, double-buffered
    __shared__ __bf16 vt_lds[128 * 64];    // [dim][key], XOR-swizzled chunks
    __shared__ __bf16 p_lds[128 * 72];     // P C-layout -> A-layout round trip

    const int tid = threadIdx.x;
    const int wave = tid >> 6, lane = tid & 63;
    const int quad = lane >> 4, l16 = lane & 15;
    const int h = blockIdx.x;
    const int ty = blockIdx.y;
    const int t = (ty < 8) ? ty : 23 - ty;
    const int qb0 = t * 128;
    const int wrow = wave * 32;
    const int kvh = h >> 3;
    const float sl2e = 0.12752039149672056f;  // (1/sqrt(128)) * log2(e)

    bf16x8 qfr[2][4];
#pragma unroll
    for (int mi = 0; mi < 2; mi++)
#pragma unroll
        for (int kk = 0; kk < 4; kk++)
            qfr[mi][kk] = *(const bf16x8*)(Q + (size_t)(qb0 + wrow + mi * 16 + l16) * D_MODEL
                                           + h * HD + kk * 32 + quad * 8);

    f32x4 acc[2][8];
#pragma unroll
    for (int mi = 0; mi < 2; mi++)
#pragma unroll
        for (int dt = 0; dt < 8; dt++) acc[mi][dt] = (f32x4)0.0f;
    float rs[2][4] = {{0.f, 0.f, 0.f, 0.f}, {0.f, 0.f, 0.f, 0.f}};

    const int nk = 2 * t + 2;

#pragma unroll
    for (int it = 0; it < 4; it++) {
        int c = tid + it * 256;
        int krow = c >> 4, kcb = c & 15;
        async16(Kb + (size_t)krow * KV_W + kvh * HD + ((kcb ^ (krow & 15)) << 3),
                k_lds[0] + c * 8);
    }
    __syncthreads();   // publish K(0)

    for (int kt = 0; kt < nk; kt++) {
        const int k0 = kt * 64;
        const int cur = kt & 1;

#pragma unroll
        for (int it = 0; it < 4; it++) {
            int c = tid + it * 256;
            int vrow = c >> 3, vcb = c & 7;
            async16(Vt + (size_t)(kvh * HD + vrow) * S_LEN + k0 + ((vcb ^ (vrow & 7)) << 3),
                    vt_lds + c * 8);
        }

        // ---- S = Q K^T from k_lds[cur] ----
        f32x4 sc[2][4];
#pragma unroll
        for (int mi = 0; mi < 2; mi++)
#pragma unroll
            for (int j = 0; j < 4; j++) sc[mi][j] = (f32x4)0.0f;
        __builtin_amdgcn_s_setprio(1);
#pragma unroll
        for (int j = 0; j < 4; j++)
#pragma unroll
            for (int kk = 0; kk < 4; kk++) {
                bf16x8 kf = *(const bf16x8*)(k_lds[cur] + (((j * 16 + l16) << 4) + ((kk * 4 + quad) ^ l16)) * 8);
                sc[0][j] = __builtin_amdgcn_mfma_f32_16x16x32_bf16(qfr[0][kk], kf, sc[0][j], 0, 0, 0);
                sc[1][j] = __builtin_amdgcn_mfma_f32_16x16x32_bf16(qfr[1][kk], kf, sc[1][j], 0, 0, 0);
            }
        __builtin_amdgcn_s_setprio(0);

        // ---- fixed-max softmax: p = exp2(s*scale*log2e), masked -> 0 ----
        const bool hasmask = (kt >= 2 * t);
#pragma unroll
        for (int mi = 0; mi < 2; mi++) {
            int rowb = qb0 + wrow + mi * 16 + quad * 4;
#pragma unroll
            for (int j = 0; j < 4; j++) {
                int kg = k0 + j * 16 + l16;
#pragma unroll
                for (int r = 0; r < 4; r++) {
                    float p = __builtin_amdgcn_exp2f(sc[mi][j][r] * sl2e);
                    if (hasmask && kg > rowb + r) p = 0.0f;
                    rs[mi][r] += p;
                    p_lds[(wrow + mi * 16 + quad * 4 + r) * 72 + j * 16 + l16] = (__bf16)p;
                }
            }
        }

        __syncthreads();   // drains V(kt) (cover: QK phase)

        if (kt + 1 < nk) {
#pragma unroll
            for (int it = 0; it < 4; it++) {
                int c = tid + it * 256;
                int krow = c >> 4, kcb = c & 15;
                async16(Kb + (size_t)(k0 + 64 + krow) * KV_W + kvh * HD + ((kcb ^ (krow & 15)) << 3),
                        k_lds[cur ^ 1] + c * 8);
            }
        }

        // ---- O += P V ----
        bf16x8 pf[2][2];
#pragma unroll
        for (int mi = 0; mi < 2; mi++)
#pragma unroll
            for (int kk = 0; kk < 2; kk++)
                pf[mi][kk] = *(const bf16x8*)(p_lds + (wrow + mi * 16 + l16) * 72 + kk * 32 + quad * 8);
        __builtin_amdgcn_s_setprio(1);
#pragma unroll
        for (int dt = 0; dt < 8; dt++)
#pragma unroll
            for (int kk = 0; kk < 2; kk++) {
                bf16x8 vf = *(const bf16x8*)(vt_lds + (((dt * 16 + l16) << 3) + ((kk * 4 + quad) ^ (l16 & 7))) * 8);
                acc[0][dt] = __builtin_amdgcn_mfma_f32_16x16x32_bf16(pf[0][kk], vf, acc[0][dt], 0, 0, 0);
                acc[1][dt] = __builtin_amdgcn_mfma_f32_16x16x32_bf16(pf[1][kk], vf, acc[1][dt], 0, 0, 0);
            }
        __builtin_amdgcn_s_setprio(0);

        __syncthreads();   // drains K(kt+1) (cover: PV phase)
    }

    float inv_l[2][4];
#pragma unroll
    for (int mi = 0; mi < 2; mi++)
#pragma unroll
        for (int r = 0; r < 4; r++) {
            float s = rs[mi][r];
#pragma unroll
            for (int m = 1; m <= 8; m <<= 1) s += __shfl_xor(s, m, 64);
            inv_l[mi][r] = 1.0f / s;
        }

#pragma unroll
    for (int mi = 0; mi < 2; mi++)
#pragma unroll
        for (int dt = 0; dt < 8; dt++)
#pragma unroll
            for (int r = 0; r < 4; r++) {
                int row = qb0 + wrow + mi * 16 + quad * 4 + r;
                int col = h * HD + dt * 16 + l16;
                O[(size_t)row * D_MODEL + col] = (__bf16)(acc[mi][dt][r] * inv_l[mi][r]);
            }
}

// ---------------- host launch ----------------
extern "C" void kernel_launch(void* const* d_in, const int* in_sizes, int n_in,
                              void* d_out, int out_size, void* d_ws, size_t ws_size,
                              hipStream_t stream) {
    const float* x = (const float*)d_in[0];
    const float* wq = (const float*)d_in[1];
    const float* wk = (const float*)d_in[2];
    const float* wv = (const float*)d_in[3];
    const float* wo = (const float*)d_in[4];
    float* out = (float*)d_out;

    char* ws = (char*)d_ws;
    size_t off = 0;
    auto alloc = [&](size_t bytes) {
        void* p = ws + off;
        off += (bytes + 255) & ~(size_t)255;
        return p;
    };
    __bf16* xb    = (__bf16*)alloc((size_t)S_LEN * D_MODEL * 2);
    __bf16* wqkvT = (__bf16*)alloc((size_t)QKV_W * D_MODEL * 2);  // [wq^T; wk^T; wv^T]
    __bf16* woT   = (__bf16*)alloc((size_t)D_MODEL * D_MODEL * 2);
    __bf16* qkb   = (__bf16*)alloc((size_t)S_LEN * QK_W * 2);     // pre-rope q|k
    __bf16* vtb   = (__bf16*)alloc((size_t)KV_W * S_LEN * 2);     // V^T
    __bf16* qb    = (__bf16*)alloc((size_t)S_LEN * D_MODEL * 2);  // post-rope Q
    __bf16* kb    = (__bf16*)alloc((size_t)S_LEN * KV_W * 2);     // post-rope K
    __bf16* ob    = (__bf16*)alloc((size_t)S_LEN * D_MODEL * 2);  // attention out

    // 1. casts / transposes
    cast_f32_bf16<<<(S_LEN * D_MODEL) / (256 * 4), 256, 0, stream>>>(x, xb, S_LEN * D_MODEL);
    transpose_cast<<<dim3(D_MODEL / 64, D_MODEL / 64), 256, 0, stream>>>(wq, wqkvT, D_MODEL, D_MODEL);
    transpose_cast<<<dim3(KV_W / 64, D_MODEL / 64), 256, 0, stream>>>(wk, wqkvT + (size_t)D_MODEL * D_MODEL, D_MODEL, KV_W);
    transpose_cast<<<dim3(KV_W / 64, D_MODEL / 64), 256, 0, stream>>>(wv, wqkvT + (size_t)QK_W * D_MODEL, D_MODEL, KV_W);
    transpose_cast<<<dim3(D_MODEL / 64, D_MODEL / 64), 256, 0, stream>>>(wo, woT, D_MODEL, D_MODEL);

    // 2. fused Q+K+V projection, 256^2 2-phase/K-tile (160 blocks; bf16 out; V transposed)
    gemm256<1><<<dim3(QKV_W / 256, S_LEN / 256), 512, 0, stream>>>(xb, wqkvT, qkb, vtb, S_LEN, QKV_W, D_MODEL);

    // 3. RoPE
    rope_cast<<<(S_LEN * NH * 64) / 256, 256, 0, stream>>>(qkb, QK_W, 0, qb, D_MODEL, NH, S_LEN * NH * 64);
    rope_cast<<<(S_LEN * NKV * 64) / 256, 256, 0, stream>>>(qkb, QK_W, D_MODEL, kb, KV_W, NKV, S_LEN * NKV * 64);

    // 4. attention (512 blocks, 2/CU, complementary-tile swizzle)
    flash_attn<<<dim3(NH, 16), 256, 0, stream>>>(qb, kb, vtb, ob);

    // 5. output projection -> fp32 d_out, 256^2 2-phase/K-tile (128 blocks)
    gemm256<0><<<dim3(D_MODEL / 256, S_LEN / 256), 512, 0, stream>>>(ob, woT, out, nullptr, S_LEN, D_MODEL, D_MODEL);
}

// Round 3
// 514.990 us; speedup vs baseline: 1.1450x; 1.0562x over previous
//
#include <hip/hip_runtime.h>
#include <math.h>

#define S_LEN 2048
#define D_MODEL 4096
#define NH 32
#define NKV 4
#define HD 128
#define KV_W (NKV * HD)        // 512
#define QK_W (D_MODEL + KV_W)  // 4608
#define QKV_W (QK_W + KV_W)    // 5120 fused q+k+v projection width

typedef float f32x4 __attribute__((ext_vector_type(4)));
typedef __bf16 bf16x8 __attribute__((ext_vector_type(8)));

// async global->LDS 16B copy. LDS dest = wave-uniform base + lane*16.
__device__ __forceinline__ void async16(const __bf16* g, __bf16* l) {
    __builtin_amdgcn_global_load_lds(
        (const __attribute__((address_space(1))) unsigned int*)g,
        (__attribute__((address_space(3))) unsigned int*)l, 16, 0, 0);
}

// ---------------- cast fp32 -> bf16 ----------------
__global__ void cast_f32_bf16(const float* __restrict__ in, __bf16* __restrict__ out, int n) {
    int i = (blockIdx.x * blockDim.x + threadIdx.x) * 4;
    if (i >= n) return;
    float4 v = *reinterpret_cast<const float4*>(in + i);
    out[i + 0] = (__bf16)v.x;
    out[i + 1] = (__bf16)v.y;
    out[i + 2] = (__bf16)v.z;
    out[i + 3] = (__bf16)v.w;
}

// ---------------- transpose + cast: in[R][C] f32 -> out[C][R] bf16 ----------------
__global__ void transpose_cast(const float* __restrict__ in, __bf16* __restrict__ out, int R, int C) {
    __shared__ float tile[64][65];
    const int tid = threadIdx.x;
    const int bx = blockIdx.x * 64, by = blockIdx.y * 64;
#pragma unroll
    for (int i = 0; i < 4; i++) {
        int idx = tid + i * 256;          // 0..1023
        int r = idx >> 4, c4 = (idx & 15) * 4;
        float4 v = *(const float4*)(in + (size_t)(by + r) * C + bx + c4);
        tile[r][c4 + 0] = v.x; tile[r][c4 + 1] = v.y;
        tile[r][c4 + 2] = v.z; tile[r][c4 + 3] = v.w;
    }
    __syncthreads();
#pragma unroll
    for (int i = 0; i < 2; i++) {
        int idx = tid + i * 256;          // 0..511
        int oc = idx >> 3, r8 = (idx & 7) * 8;  // out-row bx+oc, elems by+r8..+7
        bf16x8 v;
#pragma unroll
        for (int e = 0; e < 8; e++) v[e] = (__bf16)tile[r8 + e][oc];
        *(bf16x8*)(out + (size_t)(bx + oc) * R + by + r8) = v;
    }
}

// ---------------- pipelined bf16 MFMA GEMM: C = A[M][K] * Bt[N][K]^T ----------------
// (round-0 verified-best structure: 128^2 tile, 640/512-block grids = full chip
// with 2+ blocks/CU TLP; one __syncthreads per K-step. 256^2 variants measured
// SLOWER here: M=2048 grids only fill 160/128 of 256 CUs.)
// MODE 0: f32 [M][N] to Cp.
// MODE 1: fused QKV epilogue: n<4608 -> bf16 [M][4608] at Cp; n>=4608 -> bf16
//         transposed [n-4608][M] at Cp2 (V^T for flash).
template <int MODE>
__global__ __launch_bounds__(256, 2) void gemm_bf16(const __bf16* __restrict__ A,
                                                    const __bf16* __restrict__ Bt,
                                                    void* __restrict__ Cp, void* __restrict__ Cp2,
                                                    int M, int N, int K) {
    __shared__ __bf16 a_lds[2][128 * 32];
    __shared__ __bf16 b_lds[2][128 * 32];

    const int tid = threadIdx.x;
    const int wave = tid >> 6, lane = tid & 63;
    const int quad = lane >> 4, l16 = lane & 15;
    const int wm = wave & 1, wn = wave >> 1;
    const int m0 = blockIdx.y * 128, n0 = blockIdx.x * 128;

    f32x4 acc[4][4];
#pragma unroll
    for (int i = 0; i < 4; i++)
#pragma unroll
        for (int j = 0; j < 4; j++) acc[i][j] = (f32x4)0.0f;

    const int crow = tid >> 2, ccol = (tid & 3) * 8;
    const __bf16* Ap0 = A + (size_t)(m0 + crow) * K + ccol;
    const __bf16* Ap1 = A + (size_t)(m0 + 64 + crow) * K + ccol;
    const __bf16* Bp0 = Bt + (size_t)(n0 + crow) * K + ccol;
    const __bf16* Bp1 = Bt + (size_t)(n0 + 64 + crow) * K + ccol;

    // prestage k-tile 0 into buffer 0
    async16(Ap0, a_lds[0] + tid * 8);
    async16(Ap1, a_lds[0] + (tid + 256) * 8);
    async16(Bp0, b_lds[0] + tid * 8);
    async16(Bp1, b_lds[0] + (tid + 256) * 8);

    for (int k0 = 0; k0 < K; k0 += 32) {
        const int cur = (k0 >> 5) & 1;
        __syncthreads();   // publishes buf[cur]; all reads of buf[cur^1] are done
        if (k0 + 32 < K) {
            async16(Ap0 + k0 + 32, a_lds[cur ^ 1] + tid * 8);
            async16(Ap1 + k0 + 32, a_lds[cur ^ 1] + (tid + 256) * 8);
            async16(Bp0 + k0 + 32, b_lds[cur ^ 1] + tid * 8);
            async16(Bp1 + k0 + 32, b_lds[cur ^ 1] + (tid + 256) * 8);
        }

        bf16x8 afr[4], bfr[4];
#pragma unroll
        for (int i = 0; i < 4; i++)
            afr[i] = *(const bf16x8*)(a_lds[cur] + (wm * 64 + i * 16 + l16) * 32 + quad * 8);
#pragma unroll
        for (int j = 0; j < 4; j++)
            bfr[j] = *(const bf16x8*)(b_lds[cur] + (wn * 64 + j * 16 + l16) * 32 + quad * 8);
#pragma unroll
        for (int i = 0; i < 4; i++)
#pragma unroll
            for (int j = 0; j < 4; j++)
                acc[i][j] = __builtin_amdgcn_mfma_f32_16x16x32_bf16(afr[i], bfr[j], acc[i][j], 0, 0, 0);
    }

    const bool vregion = (MODE == 1) && (n0 >= QK_W);
#pragma unroll
    for (int i = 0; i < 4; i++)
#pragma unroll
        for (int j = 0; j < 4; j++)
#pragma unroll
            for (int r = 0; r < 4; r++) {
                int gm = m0 + wm * 64 + i * 16 + quad * 4 + r;
                int gn = n0 + wn * 64 + j * 16 + l16;
                float v = acc[i][j][r];
                if constexpr (MODE == 0) {
                    ((float*)Cp)[(size_t)gm * N + gn] = v;
                } else {
                    if (vregion)
                        ((__bf16*)Cp2)[(size_t)(gn - QK_W) * M + gm] = (__bf16)v;
                    else
                        ((__bf16*)Cp)[(size_t)gm * QK_W + gn] = (__bf16)v;
                }
            }
}

// ---------------- YaRN RoPE (bf16 strided src, bf16 out) ----------------
__global__ void rope_cast(const __bf16* __restrict__ src, int sPitch, int sOff,
                          __bf16* __restrict__ dst, int dPitch, int H, int total) {
    int idx = blockIdx.x * blockDim.x + threadIdx.x;
    if (idx >= total) return;
    int d = idx & 63;
    int t = idx >> 6;
    int h = t % H;
    int s = t / H;

    float inv = __powf(10000.0f, -(float)d * (1.0f / 64.0f));
    float wl = 6.2831853071795864f / inv;
    float r = 163840.0f / wl;
    float gamma = fminf(fmaxf((r - 1.0f) * (1.0f / 31.0f), 0.0f), 1.0f);
    float adj = inv * ((1.0f - gamma) * (1.0f / 80.0f) + gamma);
    float ang = ((float)s * adj) / 1.1992508365439246f; // / sqrt(0.1*ln(80)+1)
    float c = cosf(ang), sn = sinf(ang);

    const __bf16* b = src + (size_t)s * sPitch + sOff + h * HD;
    __bf16* o = dst + (size_t)s * dPitch + h * HD;
    float x1 = (float)b[d], x2 = (float)b[d + 64];
    o[d] = (__bf16)(x1 * c - x2 * sn);
    o[d + 64] = (__bf16)(x2 * c + x1 * sn);
}

// ---------------- flash attention v5 (single-barrier iters, causal, GQA) ----------------
// grid (NH, 16): t = ty<8 ? ty : 23-ty (complementary causal walls per CU).
// 4 waves x 32 q-rows (128-row q-tile), 64-key k-tiles, nk = 2t+2.
// v5 changes vs v4: V double-buffered; BOTH K(kt+1) and V(kt+1) staged at the
// top of iter kt (targets last read in iter kt-1, barrier-separated); exactly
// ONE raw s_barrier per iter preceded by one vmcnt(0) whose cover is the whole
// iteration (QK+softmax+PV) -- replaces v4's two __syncthreads (= two full
// vmcnt0+lgkm0 drains) per iter. P buffer shrunk to pitch-64 with XOR-swizzled
// 16B chunks (chunk ^= row&7) so total LDS = 32K(K) + 32K(V) + 16K(P) = 81920 B
// exactly -> 2 blocks/CU kept. All cross-wave hazards are read-read within an
// iter; p_lds rows are wave-private (compiler lgkm-orders write->read).
__global__ __launch_bounds__(256, 2) void flash_attn(const __bf16* __restrict__ Q,
                                                     const __bf16* __restrict__ Kb,
                                                     const __bf16* __restrict__ Vt,
                                                     __bf16* __restrict__ O) {
    __shared__ __bf16 k_lds[2][64 * 128];  // [key][dim], XOR-swizzled chunks, double-buffered
    __shared__ __bf16 vt_lds[2][128 * 64]; // [dim][key], XOR-swizzled chunks, double-buffered
    __shared__ __bf16 p_lds[128 * 64];     // P round trip, pitch 64, XOR-swizzled chunks

    const int tid = threadIdx.x;
    const int wave = tid >> 6, lane = tid & 63;
    const int quad = lane >> 4, l16 = lane & 15;
    const int h = blockIdx.x;
    const int ty = blockIdx.y;
    const int t = (ty < 8) ? ty : 23 - ty;
    const int qb0 = t * 128;
    const int wrow = wave * 32;
    const int kvh = h >> 3;
    const float sl2e = 0.12752039149672056f;  // (1/sqrt(128)) * log2(e)

    // Q fragments in registers (A-layout), loaded once
    bf16x8 qfr[2][4];
#pragma unroll
    for (int mi = 0; mi < 2; mi++)
#pragma unroll
        for (int kk = 0; kk < 4; kk++)
            qfr[mi][kk] = *(const bf16x8*)(Q + (size_t)(qb0 + wrow + mi * 16 + l16) * D_MODEL
                                           + h * HD + kk * 32 + quad * 8);

    f32x4 acc[2][8];
#pragma unroll
    for (int mi = 0; mi < 2; mi++)
#pragma unroll
        for (int dt = 0; dt < 8; dt++) acc[mi][dt] = (f32x4)0.0f;
    float rs[2][4] = {{0.f, 0.f, 0.f, 0.f}, {0.f, 0.f, 0.f, 0.f}};

    const int nk = 2 * t + 2;

    // staging helpers (per-thread source indices)
    const int kc = tid, krow = kc >> 2, kcb0 = kc & 3;       // unused split form
    (void)kc; (void)krow; (void)kcb0;

    // prologue: stage K(0) -> k[0], V(0) -> v[0]
#pragma unroll
    for (int it = 0; it < 4; it++) {
        int c = tid + it * 256;
        int kr = c >> 4, kb = c & 15;
        async16(Kb + (size_t)kr * KV_W + kvh * HD + ((kb ^ (kr & 15)) << 3),
                k_lds[0] + c * 8);
    }
#pragma unroll
    for (int it = 0; it < 4; it++) {
        int c = tid + it * 256;
        int vr = c >> 3, vb = c & 7;
        async16(Vt + (size_t)(kvh * HD + vr) * S_LEN + 0 + ((vb ^ (vr & 7)) << 3),
                vt_lds[0] + c * 8);
    }
    asm volatile("s_waitcnt vmcnt(0)" ::: "memory");
    __builtin_amdgcn_sched_barrier(0);
    __builtin_amdgcn_s_barrier();

    for (int kt = 0; kt < nk; kt++) {
        const int k0 = kt * 64;
        const int cur = kt & 1;

        // stage K(kt+1), V(kt+1) -> buffers [cur^1] (last read in iter kt-1,
        // separated by the end-of-iter barrier). Full-iter latency cover.
        if (kt + 1 < nk) {
#pragma unroll
            for (int it = 0; it < 4; it++) {
                int c = tid + it * 256;
                int kr = c >> 4, kb = c & 15;
                async16(Kb + (size_t)(k0 + 64 + kr) * KV_W + kvh * HD + ((kb ^ (kr & 15)) << 3),
                        k_lds[cur ^ 1] + c * 8);
            }
#pragma unroll
            for (int it = 0; it < 4; it++) {
                int c = tid + it * 256;
                int vr = c >> 3, vb = c & 7;
                async16(Vt + (size_t)(kvh * HD + vr) * S_LEN + (k0 + 64) + ((vb ^ (vr & 7)) << 3),
                        vt_lds[cur ^ 1] + c * 8);
            }
        }

        // ---- S = Q K^T from k_lds[cur] ----
        f32x4 sc[2][4];
#pragma unroll
        for (int mi = 0; mi < 2; mi++)
#pragma unroll
            for (int j = 0; j < 4; j++) sc[mi][j] = (f32x4)0.0f;
        __builtin_amdgcn_s_setprio(1);
#pragma unroll
        for (int j = 0; j < 4; j++)
#pragma unroll
            for (int kk = 0; kk < 4; kk++) {
                bf16x8 kf = *(const bf16x8*)(k_lds[cur] + (((j * 16 + l16) << 4) + ((kk * 4 + quad) ^ l16)) * 8);
                sc[0][j] = __builtin_amdgcn_mfma_f32_16x16x32_bf16(qfr[0][kk], kf, sc[0][j], 0, 0, 0);
                sc[1][j] = __builtin_amdgcn_mfma_f32_16x16x32_bf16(qfr[1][kk], kf, sc[1][j], 0, 0, 0);
            }
        __builtin_amdgcn_s_setprio(0);

        // ---- fixed-max softmax: p = exp2(s*scale*log2e), masked -> 0 ----
        const bool hasmask = (kt >= 2 * t);
#pragma unroll
        for (int mi = 0; mi < 2; mi++) {
            int rowb = qb0 + wrow + mi * 16 + quad * 4;
#pragma unroll
            for (int j = 0; j < 4; j++) {
                int kg = k0 + j * 16 + l16;
#pragma unroll
                for (int r = 0; r < 4; r++) {
                    float p = __builtin_amdgcn_exp2f(sc[mi][j][r] * sl2e);
                    if (hasmask && kg > rowb + r) p = 0.0f;
                    rs[mi][r] += p;
                    int pr = wrow + mi * 16 + quad * 4 + r;
                    int ch = (2 * j + (l16 >> 3)) ^ (pr & 7);
                    p_lds[pr * 64 + ch * 8 + (l16 & 7)] = (__bf16)p;
                }
            }
        }

        // ---- O += P V from vt_lds[cur] (p rows wave-private; lgkm orders) ----
        bf16x8 pf[2][2];
#pragma unroll
        for (int mi = 0; mi < 2; mi++)
#pragma unroll
            for (int kk = 0; kk < 2; kk++) {
                int row = wrow + mi * 16 + l16;
                pf[mi][kk] = *(const bf16x8*)(p_lds + row * 64 + (((kk * 4 + quad) ^ (row & 7)) << 3));
            }
        __builtin_amdgcn_s_setprio(1);
#pragma unroll
        for (int dt = 0; dt < 8; dt++)
#pragma unroll
            for (int kk = 0; kk < 2; kk++) {
                bf16x8 vf = *(const bf16x8*)(vt_lds[cur] + (((dt * 16 + l16) << 3) + ((kk * 4 + quad) ^ (l16 & 7))) * 8);
                acc[0][dt] = __builtin_amdgcn_mfma_f32_16x16x32_bf16(pf[0][kk], vf, acc[0][dt], 0, 0, 0);
                acc[1][dt] = __builtin_amdgcn_mfma_f32_16x16x32_bf16(pf[1][kk], vf, acc[1][dt], 0, 0, 0);
            }
        __builtin_amdgcn_s_setprio(0);

        // single end-of-iter sync: staged K/V(kt+1) ready (full-iter cover);
        // all reads of [cur] buffers drained (lgkm before their MFMAs).
        if (kt + 1 < nk) { asm volatile("s_waitcnt vmcnt(0)" ::: "memory"); }
        __builtin_amdgcn_sched_barrier(0);
        __builtin_amdgcn_s_barrier();
    }

    // ---- final row-sum reduction across l16 (once per block) ----
    float inv_l[2][4];
#pragma unroll
    for (int mi = 0; mi < 2; mi++)
#pragma unroll
        for (int r = 0; r < 4; r++) {
            float s = rs[mi][r];
#pragma unroll
            for (int m = 1; m <= 8; m <<= 1) s += __shfl_xor(s, m, 64);
            inv_l[mi][r] = 1.0f / s;
        }

#pragma unroll
    for (int mi = 0; mi < 2; mi++)
#pragma unroll
        for (int dt = 0; dt < 8; dt++)
#pragma unroll
            for (int r = 0; r < 4; r++) {
                int row = qb0 + wrow + mi * 16 + quad * 4 + r;
                int col = h * HD + dt * 16 + l16;
                O[(size_t)row * D_MODEL + col] = (__bf16)(acc[mi][dt][r] * inv_l[mi][r]);
            }
}

// ---------------- host launch ----------------
extern "C" void kernel_launch(void* const* d_in, const int* in_sizes, int n_in,
                              void* d_out, int out_size, void* d_ws, size_t ws_size,
                              hipStream_t stream) {
    const float* x = (const float*)d_in[0];
    const float* wq = (const float*)d_in[1];
    const float* wk = (const float*)d_in[2];
    const float* wv = (const float*)d_in[3];
    const float* wo = (const float*)d_in[4];
    float* out = (float*)d_out;

    char* ws = (char*)d_ws;
    size_t off = 0;
    auto alloc = [&](size_t bytes) {
        void* p = ws + off;
        off += (bytes + 255) & ~(size_t)255;
        return p;
    };
    __bf16* xb    = (__bf16*)alloc((size_t)S_LEN * D_MODEL * 2);
    __bf16* wqkvT = (__bf16*)alloc((size_t)QKV_W * D_MODEL * 2);  // [wq^T; wk^T; wv^T]
    __bf16* woT   = (__bf16*)alloc((size_t)D_MODEL * D_MODEL * 2);
    __bf16* qkb   = (__bf16*)alloc((size_t)S_LEN * QK_W * 2);     // pre-rope q|k
    __bf16* vtb   = (__bf16*)alloc((size_t)KV_W * S_LEN * 2);     // V^T
    __bf16* qb    = (__bf16*)alloc((size_t)S_LEN * D_MODEL * 2);  // post-rope Q
    __bf16* kb    = (__bf16*)alloc((size_t)S_LEN * KV_W * 2);     // post-rope K
    __bf16* ob    = (__bf16*)alloc((size_t)S_LEN * D_MODEL * 2);  // attention out

    // 1. casts / transposes
    cast_f32_bf16<<<(S_LEN * D_MODEL) / (256 * 4), 256, 0, stream>>>(x, xb, S_LEN * D_MODEL);
    transpose_cast<<<dim3(D_MODEL / 64, D_MODEL / 64), 256, 0, stream>>>(wq, wqkvT, D_MODEL, D_MODEL);
    transpose_cast<<<dim3(KV_W / 64, D_MODEL / 64), 256, 0, stream>>>(wk, wqkvT + (size_t)D_MODEL * D_MODEL, D_MODEL, KV_W);
    transpose_cast<<<dim3(KV_W / 64, D_MODEL / 64), 256, 0, stream>>>(wv, wqkvT + (size_t)QK_W * D_MODEL, D_MODEL, KV_W);
    transpose_cast<<<dim3(D_MODEL / 64, D_MODEL / 64), 256, 0, stream>>>(wo, woT, D_MODEL, D_MODEL);

    // 2. fused Q+K+V projection (bf16 out; V written transposed) -- 640 blocks
    gemm_bf16<1><<<dim3(QKV_W / 128, S_LEN / 128), 256, 0, stream>>>(xb, wqkvT, qkb, vtb, S_LEN, QKV_W, D_MODEL);

    // 3. RoPE
    rope_cast<<<(S_LEN * NH * 64) / 256, 256, 0, stream>>>(qkb, QK_W, 0, qb, D_MODEL, NH, S_LEN * NH * 64);
    rope_cast<<<(S_LEN * NKV * 64) / 256, 256, 0, stream>>>(qkb, QK_W, D_MODEL, kb, KV_W, NKV, S_LEN * NKV * 64);

    // 4. attention (512 blocks, 2/CU, complementary-tile swizzle)
    flash_attn<<<dim3(NH, 16), 256, 0, stream>>>(qb, kb, vtb, ob);

    // 5. output projection -> fp32 d_out -- 512 blocks
    gemm_bf16<0><<<dim3(D_MODEL / 128, S_LEN / 128), 256, 0, stream>>>(ob, woT, out, nullptr, S_LEN, D_MODEL, D_MODEL);
}